// Round 12
// baseline (76.470 us; speedup 1.0000x reference)
//
#include <hip/hip_runtime.h>

// Problem shape (fixed by reference setup_inputs):
//   bert_emb:    [B=4, Lp=256, D=768] fp32
//   pieces2word: [B=4, Lw=200, Lp=256] int32 (0/1)
//   out:         [B=4, Lw=200, D=768] fp32
// out[b,w,d] = max over {p : mask[b,w,p]!=0} of emb[b,p,d], else global min(emb).
//
// R22 — R21 (best, 64.03) + merge-tail trim (ONLY changes):
//  (a) skip-own-write: finalize wave j keeps acc[j] in registers, skips the
//      sacc[j][j] write (5 of 40 ds_writes), and reads the other 7 segments
//      via rotated indices (j+1+t)&7 — branch-free read path.
//  (b) tree-fold with v_max3: 8-input fold = 4 ops depth 2 (was 7 serial
//      fmaxf depth 7) — shorter epilogue dependency chain.
//  Floor model (R21 accounting): on 2-block CUs, L2 stream 512KB/CU @
//  ~135GB/s/CU share ~3.8us || VALU 7680cy ~3.2us, + ramp ~1.2 + tail ~0.5
//  + launch ~1.5 => ~7.2us kernel. L2 stream irreducible here: waves read
//  DISJOINT rows (no intra-block reuse to stage), W-up fails occupancy
//  (R14/R15). This trim targets the last addressable term (tail).
//  Ledger: confirmed = v_max3 merge (R12), float4 amortization (R13),
//  tail trim (R18), XCD swizzle (R19), epilogue hoist + nt stores (R21).
//  Falsified = branch-skip (R11), L2-cut-via-geometry (R14/R15), SALU gate
//  (R16), explicit pipeline (R17).
//  Geometry: 480 blocks x 512 thr, float4, W=5, PPS=32, packed ballots,
//  XCD swizzle virt=(blk&7)*60+(blk>>3), cndmask gate + v_max3 pair-merge
//  (1.5 VALU/elem), single-pass 40KB LDS merge.
//  acc init = -inf bit-exact; empty-mask word -> global-min fallback.

#define B_  4
#define LP_ 256
#define LW_ 200
#define D_  768
#define D4_ (D_ / 4)              // 192 float4 per row
#define CHUNKS 3                  // 3 chunks x 256 floats (1 float4 per lane)
#define W_  5                     // words per block
#define WG_ (LW_ / W_)            // 40 word-groups
#define NBLK (B_ * CHUNKS * WG_)  // 480 blocks = 8 XCDs x 60
#define SEGS 8                    // waves (piece segments) per block
#define PPS 32                    // pieces per segment

typedef float v4f __attribute__((ext_vector_type(4)));

__device__ __forceinline__ void max3_inplace(float& d, float a, float b) {
    asm("v_max3_f32 %0, %1, %2, %3" : "=v"(d) : "v"(d), "v"(a), "v"(b));
}
__device__ __forceinline__ float max3v(float a, float b, float c) {
    float d;
    asm("v_max3_f32 %0, %1, %2, %3" : "=v"(d) : "v"(a), "v"(b), "v"(c));
    return d;
}

__global__ __launch_bounds__(512) void word_max_scan(
    const float* __restrict__ emb, const int* __restrict__ p2w,
    float* __restrict__ out)
{
    // XCD-locality swizzle: hw XCD = blockIdx.x % 8 (round-robin, m09).
    const int blk   = (blockIdx.x & 7) * (NBLK / 8) + (blockIdx.x >> 3);
    const int wg    = blk % WG_;
    const int rest  = blk / WG_;
    const int chunk = rest % CHUNKS;
    const int b     = rest / CHUNKS;
    const int lane  = threadIdx.x & 63;
    const int s     = threadIdx.x >> 6;     // piece segment 0..7
    const int w0    = wg * W_;

    // Packed ballots: one 64-bit ballot covers TWO words (lo lanes -> word
    // jp, hi lanes -> word jp+1); piece index = s*PPS + (lane&31) for both.
    unsigned int m[W_];
    const int pc = s * PPS + (lane & 31);
    #pragma unroll
    for (int jp = 0; jp < W_; jp += 2) {
        const int jhi = (jp + 1 < W_) ? (jp + 1) : jp;  // last: both halves jp
        const int j   = (lane >= 32) ? jhi : jp;
        const int* mrow = p2w + (b * LW_ + w0 + j) * LP_;
        unsigned long long bal = __ballot(mrow[pc] != 0);
        m[jp] = (unsigned int)bal;
        if (jp + 1 < W_) m[jp + 1] = (unsigned int)(bal >> 32);
    }

    // Early empty-word check for the finalize waves (s < W_): the p2w row
    // is cache-hot from the ballot phase; latency hides under the main
    // loop. Carried as one wave-uniform bool to the epilogue.
    bool word_empty = false;
    if (s < W_) {
        const int4 mv =
            ((const int4*)(p2w + (b * LW_ + w0 + s) * LP_))[lane];
        word_empty =
            (__ballot((mv.x | mv.y | mv.z | mv.w) != 0) == 0ull);
    }

    const float ninf = __uint_as_float(0xFF800000u);
    float4 acc[W_];
    #pragma unroll
    for (int j = 0; j < W_; ++j) acc[j] = make_float4(ninf, ninf, ninf, ninf);

    // Wave's row stream: rows [32s, 32s+32), column = chunk*64 + lane (float4).
    const float4* rps = (const float4*)(emb + (size_t)b * LP_ * D_)
                        + chunk * 64 + lane + (size_t)(s * PPS) * D4_;

    #pragma unroll
    for (int g = 0; g < PPS; g += 8) {
        float4 v[8];
        #pragma unroll
        for (int k = 0; k < 8; ++k)
            v[k] = rps[(size_t)(g + k) * D4_];
        #pragma unroll
        for (int k = 0; k < 8; k += 2) {
            #pragma unroll
            for (int j = 0; j < W_; ++j) {
                const bool b0 = (m[j] >> (g + k))     & 1u;  // uniform
                const bool b1 = (m[j] >> (g + k + 1)) & 1u;  // uniform
                // One VCC per bit gates FOUR cndmasks (amortized SALU).
                float sx0 = b0 ? v[k].x     : ninf;
                float sy0 = b0 ? v[k].y     : ninf;
                float sz0 = b0 ? v[k].z     : ninf;
                float sw0 = b0 ? v[k].w     : ninf;
                float sx1 = b1 ? v[k + 1].x : ninf;
                float sy1 = b1 ? v[k + 1].y : ninf;
                float sz1 = b1 ? v[k + 1].z : ninf;
                float sw1 = b1 ? v[k + 1].w : ninf;
                max3_inplace(acc[j].x, sx0, sx1);
                max3_inplace(acc[j].y, sy0, sy1);
                max3_inplace(acc[j].z, sz0, sz1);
                max3_inplace(acc[j].w, sw0, sw1);
            }
        }
    }

    // Merge the 8 segments via LDS (8 x 5 x 64 x 16B = 40 KB).
    // (a) Finalize wave j (s < W_) keeps acc[s] in registers: skip its own
    // sacc[s][s] write (uniform branch, compile-time unrolled j).
    __shared__ float4 sacc[SEGS][W_][64];
    #pragma unroll
    for (int j = 0; j < W_; ++j)
        if (s != j) sacc[s][j][lane] = acc[j];
    __syncthreads();

    // Wave j (< W_) finalizes word j.
    if (s < W_) {
        const int j = s;
        // Rotated branch-free reads: segs (j+1+t)&7, t=0..6 — exactly the
        // 7 segments other waves published for word j.
        float4 q[SEGS - 1];
        #pragma unroll
        for (int t = 0; t < SEGS - 1; ++t)
            q[t] = sacc[(j + 1 + t) & 7][j][lane];

        // (b) Tree fold, depth 2: r = max(acc[j], q0..q6).
        float4 r;
        {
            float a0 = max3v(acc[j].x, q[0].x, q[1].x);
            float b0 = max3v(q[2].x, q[3].x, q[4].x);
            float c0 = fmaxf(q[5].x, q[6].x);
            r.x = max3v(a0, b0, c0);
            float a1 = max3v(acc[j].y, q[0].y, q[1].y);
            float b1 = max3v(q[2].y, q[3].y, q[4].y);
            float c1 = fmaxf(q[5].y, q[6].y);
            r.y = max3v(a1, b1, c1);
            float a2 = max3v(acc[j].z, q[0].z, q[1].z);
            float b2 = max3v(q[2].z, q[3].z, q[4].z);
            float c2 = fmaxf(q[5].z, q[6].z);
            r.z = max3v(a2, b2, c2);
            float a3 = max3v(acc[j].w, q[0].w, q[1].w);
            float b3 = max3v(q[2].w, q[3].w, q[4].w);
            float c3 = fmaxf(q[5].w, q[6].w);
            r.w = max3v(a3, b3, c3);
        }

        if (word_empty) {
            // Never taken for the fixed inputs; correct fallback = global
            // min over ALL of emb (reference min_value semantics).
            const float4* x = (const float4*)emb;
            const int n4 = (B_ * LP_ * D_) / 4;
            float mn = __uint_as_float(0x7F800000u);  // +inf
            for (int i = lane; i < n4; i += 64) {
                float4 vv = x[i];
                mn = fminf(mn, fminf(fminf(vv.x, vv.y), fminf(vv.z, vv.w)));
            }
            #pragma unroll
            for (int off = 32; off > 0; off >>= 1)
                mn = fminf(mn, __shfl_down(mn, off, 64));
            mn = __shfl(mn, 0, 64);
            r = make_float4(mn, mn, mn, mn);
        }

        // Write-once output: nontemporal dwordx4 (clang native vector type;
        // __builtin_nontemporal_store rejects HIP_vector_type).
        v4f* op = (v4f*)((float4*)out + (size_t)(b * LW_ + w0 + j) * D4_
                         + chunk * 64 + lane);
        v4f rv;
        rv.x = r.x; rv.y = r.y; rv.z = r.z; rv.w = r.w;
        __builtin_nontemporal_store(rv, op);
    }
}

extern "C" void kernel_launch(void* const* d_in, const int* in_sizes, int n_in,
                              void* d_out, int out_size, void* d_ws, size_t ws_size,
                              hipStream_t stream) {
    const float* emb = (const float*)d_in[0];
    const int*   p2w = (const int*)d_in[1];
    float*       out = (float*)d_out;
    (void)d_ws; (void)ws_size;

    word_max_scan<<<NBLK, 512, 0, stream>>>(emb, p2w, out);
}

// Round 13
// 64.955 us; speedup vs baseline: 1.1773x; 1.1773x over previous
//
#include <hip/hip_runtime.h>

// Problem shape (fixed by reference setup_inputs):
//   bert_emb:    [B=4, Lp=256, D=768] fp32
//   pieces2word: [B=4, Lw=200, Lp=256] int32 (0/1)
//   out:         [B=4, Lw=200, D=768] fp32
// out[b,w,d] = max over {p : mask[b,w,p]!=0} of emb[b,p,d], else global min(emb).
//
// R23 — R21 (best, 64.03) + tree-fold epilogue ONLY.
//  R22 post-mortem (+12.4us): epilogue read acc[j] with RUNTIME j=s ->
//  rule #20: runtime-indexed register array demoted the whole accumulator
//  to scratch; every main-loop accumulate became a scratch RMW. Fix: never
//  index acc[] at runtime. Skip-own-write dropped (it required that read;
//  saved only 5 ds_writes). Tree-fold kept: all 8 segments read from LDS
//  (runtime j legal in LDS addressing), folded with v_max3 at depth 2
//  (4 ops) vs 7 serial fmaxf (depth 7).
//  Ledger: confirmed = v_max3 merge (R12), float4 amortization (R13),
//  tail trim (R18), XCD swizzle (R19), epilogue hoist + nt stores (R21).
//  Falsified = branch-skip (R11), L2-cut-via-geometry (R14/R15), SALU gate
//  (R16), explicit pipeline (R17), runtime-acc tail trim (R22, rule #20).
//  Geometry: 480 blocks x 512 thr, float4, W=5, PPS=32, packed ballots,
//  XCD swizzle virt=(blk&7)*60+(blk>>3), cndmask gate + v_max3 pair-merge
//  (1.5 VALU/elem), single-pass 40KB LDS merge.
//  acc init = -inf bit-exact; empty-mask word -> global-min fallback.

#define B_  4
#define LP_ 256
#define LW_ 200
#define D_  768
#define D4_ (D_ / 4)              // 192 float4 per row
#define CHUNKS 3                  // 3 chunks x 256 floats (1 float4 per lane)
#define W_  5                     // words per block
#define WG_ (LW_ / W_)            // 40 word-groups
#define NBLK (B_ * CHUNKS * WG_)  // 480 blocks = 8 XCDs x 60
#define SEGS 8                    // waves (piece segments) per block
#define PPS 32                    // pieces per segment

typedef float v4f __attribute__((ext_vector_type(4)));

__device__ __forceinline__ void max3_inplace(float& d, float a, float b) {
    asm("v_max3_f32 %0, %1, %2, %3" : "=v"(d) : "v"(d), "v"(a), "v"(b));
}
__device__ __forceinline__ float max3v(float a, float b, float c) {
    float d;
    asm("v_max3_f32 %0, %1, %2, %3" : "=v"(d) : "v"(a), "v"(b), "v"(c));
    return d;
}

__global__ __launch_bounds__(512) void word_max_scan(
    const float* __restrict__ emb, const int* __restrict__ p2w,
    float* __restrict__ out)
{
    // XCD-locality swizzle: hw XCD = blockIdx.x % 8 (round-robin, m09).
    const int blk   = (blockIdx.x & 7) * (NBLK / 8) + (blockIdx.x >> 3);
    const int wg    = blk % WG_;
    const int rest  = blk / WG_;
    const int chunk = rest % CHUNKS;
    const int b     = rest / CHUNKS;
    const int lane  = threadIdx.x & 63;
    const int s     = threadIdx.x >> 6;     // piece segment 0..7
    const int w0    = wg * W_;

    // Packed ballots: one 64-bit ballot covers TWO words (lo lanes -> word
    // jp, hi lanes -> word jp+1); piece index = s*PPS + (lane&31) for both.
    unsigned int m[W_];
    const int pc = s * PPS + (lane & 31);
    #pragma unroll
    for (int jp = 0; jp < W_; jp += 2) {
        const int jhi = (jp + 1 < W_) ? (jp + 1) : jp;  // last: both halves jp
        const int j   = (lane >= 32) ? jhi : jp;
        const int* mrow = p2w + (b * LW_ + w0 + j) * LP_;
        unsigned long long bal = __ballot(mrow[pc] != 0);
        m[jp] = (unsigned int)bal;
        if (jp + 1 < W_) m[jp + 1] = (unsigned int)(bal >> 32);
    }

    // Early empty-word check for the finalize waves (s < W_): the p2w row
    // is cache-hot from the ballot phase; latency hides under the main
    // loop. Carried as one wave-uniform bool to the epilogue.
    bool word_empty = false;
    if (s < W_) {
        const int4 mv =
            ((const int4*)(p2w + (b * LW_ + w0 + s) * LP_))[lane];
        word_empty =
            (__ballot((mv.x | mv.y | mv.z | mv.w) != 0) == 0ull);
    }

    const float ninf = __uint_as_float(0xFF800000u);
    float4 acc[W_];
    #pragma unroll
    for (int j = 0; j < W_; ++j) acc[j] = make_float4(ninf, ninf, ninf, ninf);

    // Wave's row stream: rows [32s, 32s+32), column = chunk*64 + lane (float4).
    const float4* rps = (const float4*)(emb + (size_t)b * LP_ * D_)
                        + chunk * 64 + lane + (size_t)(s * PPS) * D4_;

    #pragma unroll
    for (int g = 0; g < PPS; g += 8) {
        float4 v[8];
        #pragma unroll
        for (int k = 0; k < 8; ++k)
            v[k] = rps[(size_t)(g + k) * D4_];
        #pragma unroll
        for (int k = 0; k < 8; k += 2) {
            #pragma unroll
            for (int j = 0; j < W_; ++j) {
                const bool b0 = (m[j] >> (g + k))     & 1u;  // uniform
                const bool b1 = (m[j] >> (g + k + 1)) & 1u;  // uniform
                // One VCC per bit gates FOUR cndmasks (amortized SALU).
                float sx0 = b0 ? v[k].x     : ninf;
                float sy0 = b0 ? v[k].y     : ninf;
                float sz0 = b0 ? v[k].z     : ninf;
                float sw0 = b0 ? v[k].w     : ninf;
                float sx1 = b1 ? v[k + 1].x : ninf;
                float sy1 = b1 ? v[k + 1].y : ninf;
                float sz1 = b1 ? v[k + 1].z : ninf;
                float sw1 = b1 ? v[k + 1].w : ninf;
                max3_inplace(acc[j].x, sx0, sx1);
                max3_inplace(acc[j].y, sy0, sy1);
                max3_inplace(acc[j].z, sz0, sz1);
                max3_inplace(acc[j].w, sw0, sw1);
            }
        }
    }

    // Merge the 8 segments via LDS (8 x 5 x 64 x 16B = 40 KB).
    __shared__ float4 sacc[SEGS][W_][64];
    #pragma unroll
    for (int j = 0; j < W_; ++j) sacc[s][j][lane] = acc[j];
    __syncthreads();

    // Wave j (< W_) finalizes word j. All inputs from LDS (runtime j only
    // in LDS addresses — acc[] is never runtime-indexed, rule #20).
    if (s < W_) {
        const int j = s;
        const float4 q0 = sacc[0][j][lane];
        const float4 q1 = sacc[1][j][lane];
        const float4 q2 = sacc[2][j][lane];
        const float4 q3 = sacc[3][j][lane];
        const float4 q4 = sacc[4][j][lane];
        const float4 q5 = sacc[5][j][lane];
        const float4 q6 = sacc[6][j][lane];
        const float4 q7 = sacc[7][j][lane];

        // Tree fold, depth 2: r = max(q0..q7) via v_max3.
        float4 r;
        r.x = max3v(max3v(q0.x, q1.x, q2.x), max3v(q3.x, q4.x, q5.x),
                    fmaxf(q6.x, q7.x));
        r.y = max3v(max3v(q0.y, q1.y, q2.y), max3v(q3.y, q4.y, q5.y),
                    fmaxf(q6.y, q7.y));
        r.z = max3v(max3v(q0.z, q1.z, q2.z), max3v(q3.z, q4.z, q5.z),
                    fmaxf(q6.z, q7.z));
        r.w = max3v(max3v(q0.w, q1.w, q2.w), max3v(q3.w, q4.w, q5.w),
                    fmaxf(q6.w, q7.w));

        if (word_empty) {
            // Never taken for the fixed inputs; correct fallback = global
            // min over ALL of emb (reference min_value semantics).
            const float4* x = (const float4*)emb;
            const int n4 = (B_ * LP_ * D_) / 4;
            float mn = __uint_as_float(0x7F800000u);  // +inf
            for (int i = lane; i < n4; i += 64) {
                float4 vv = x[i];
                mn = fminf(mn, fminf(fminf(vv.x, vv.y), fminf(vv.z, vv.w)));
            }
            #pragma unroll
            for (int off = 32; off > 0; off >>= 1)
                mn = fminf(mn, __shfl_down(mn, off, 64));
            mn = __shfl(mn, 0, 64);
            r = make_float4(mn, mn, mn, mn);
        }

        // Write-once output: nontemporal dwordx4 (clang native vector type;
        // __builtin_nontemporal_store rejects HIP_vector_type).
        v4f* op = (v4f*)((float4*)out + (size_t)(b * LW_ + w0 + j) * D4_
                         + chunk * 64 + lane);
        v4f rv;
        rv.x = r.x; rv.y = r.y; rv.z = r.z; rv.w = r.w;
        __builtin_nontemporal_store(rv, op);
    }
}

extern "C" void kernel_launch(void* const* d_in, const int* in_sizes, int n_in,
                              void* d_out, int out_size, void* d_ws, size_t ws_size,
                              hipStream_t stream) {
    const float* emb = (const float*)d_in[0];
    const int*   p2w = (const int*)d_in[1];
    float*       out = (float*)d_out;
    (void)d_ws; (void)ws_size;

    word_max_scan<<<NBLK, 512, 0, stream>>>(emb, p2w, out);
}

// Round 14
// 64.419 us; speedup vs baseline: 1.1871x; 1.0083x over previous
//
#include <hip/hip_runtime.h>

// Problem shape (fixed by reference setup_inputs):
//   bert_emb:    [B=4, Lp=256, D=768] fp32
//   pieces2word: [B=4, Lw=200, Lp=256] int32 (0/1)
//   out:         [B=4, Lw=200, D=768] fp32
// out[b,w,d] = max over {p : mask[b,w,p]!=0} of emb[b,p,d], else global min(emb).
//
// R24 — REVERT to R21 (best measured: 64.03 us). Final configuration.
//  R23 post-mortem: v_max3 tree-fold in the epilogue REGRESSED (+0.9us) —
//  the serial fmaxf chain let the compiler overlap ds_read latency with
//  staggered lgkmcnt waits; the asm tree pinned the schedule and serialized
//  the 8 LDS reads. Epilogue tree-fold falsified. Restoring R21 exactly.
//  Ledger (final): confirmed = v_max3 pair-merge in main loop (R12),
//  float4 amortization (R13), packed ballots + smask removal (R18),
//  XCD swizzle (R19), epilogue hoist + nontemporal stores (R21).
//  Falsified = uniform-branch skip (R11), L2-cut-via-geometry (R14/R15:
//  occupancy/VGPR collapse), SALU-free bfe/bfi gate (R16), explicit
//  software pipeline (R17: compiler already does it), runtime-indexed acc
//  (R22: rule #20 scratch demotion), epilogue tree-fold (R23).
//  Floor model: on 2-block CUs, L2 stream 512KB/CU ~3.8us || VALU 7680cy
//  ~3.2us, + cold ramp ~1.2 + tail ~0.5 + launch ~1.5 => ~7us kernel in a
//  ~57us harness constant.
//  Geometry: 480 blocks x 512 thr, float4, W=5, PPS=32, packed ballots,
//  XCD swizzle virt=(blk&7)*60+(blk>>3), cndmask gate + v_max3 pair-merge
//  (1.5 VALU/elem), single-pass 40KB LDS merge, serial-fmaxf epilogue fold,
//  nontemporal dwordx4 stores.
//  acc init = -inf bit-exact; empty-mask word -> global-min fallback.

#define B_  4
#define LP_ 256
#define LW_ 200
#define D_  768
#define D4_ (D_ / 4)              // 192 float4 per row
#define CHUNKS 3                  // 3 chunks x 256 floats (1 float4 per lane)
#define W_  5                     // words per block
#define WG_ (LW_ / W_)            // 40 word-groups
#define NBLK (B_ * CHUNKS * WG_)  // 480 blocks = 8 XCDs x 60
#define SEGS 8                    // waves (piece segments) per block
#define PPS 32                    // pieces per segment

typedef float v4f __attribute__((ext_vector_type(4)));

__device__ __forceinline__ void max3_inplace(float& d, float a, float b) {
    asm("v_max3_f32 %0, %1, %2, %3" : "=v"(d) : "v"(d), "v"(a), "v"(b));
}

__global__ __launch_bounds__(512) void word_max_scan(
    const float* __restrict__ emb, const int* __restrict__ p2w,
    float* __restrict__ out)
{
    // XCD-locality swizzle: hw XCD = blockIdx.x % 8 (round-robin, m09).
    const int blk   = (blockIdx.x & 7) * (NBLK / 8) + (blockIdx.x >> 3);
    const int wg    = blk % WG_;
    const int rest  = blk / WG_;
    const int chunk = rest % CHUNKS;
    const int b     = rest / CHUNKS;
    const int lane  = threadIdx.x & 63;
    const int s     = threadIdx.x >> 6;     // piece segment 0..7
    const int w0    = wg * W_;

    // Packed ballots: one 64-bit ballot covers TWO words (lo lanes -> word
    // jp, hi lanes -> word jp+1); piece index = s*PPS + (lane&31) for both.
    unsigned int m[W_];
    const int pc = s * PPS + (lane & 31);
    #pragma unroll
    for (int jp = 0; jp < W_; jp += 2) {
        const int jhi = (jp + 1 < W_) ? (jp + 1) : jp;  // last: both halves jp
        const int j   = (lane >= 32) ? jhi : jp;
        const int* mrow = p2w + (b * LW_ + w0 + j) * LP_;
        unsigned long long bal = __ballot(mrow[pc] != 0);
        m[jp] = (unsigned int)bal;
        if (jp + 1 < W_) m[jp + 1] = (unsigned int)(bal >> 32);
    }

    // Early empty-word check for the finalize waves (s < W_): the p2w row
    // is cache-hot from the ballot phase; latency hides under the main
    // loop. Carried as one wave-uniform bool to the epilogue.
    bool word_empty = false;
    if (s < W_) {
        const int4 mv =
            ((const int4*)(p2w + (b * LW_ + w0 + s) * LP_))[lane];
        word_empty =
            (__ballot((mv.x | mv.y | mv.z | mv.w) != 0) == 0ull);
    }

    const float ninf = __uint_as_float(0xFF800000u);
    float4 acc[W_];
    #pragma unroll
    for (int j = 0; j < W_; ++j) acc[j] = make_float4(ninf, ninf, ninf, ninf);

    // Wave's row stream: rows [32s, 32s+32), column = chunk*64 + lane (float4).
    const float4* rps = (const float4*)(emb + (size_t)b * LP_ * D_)
                        + chunk * 64 + lane + (size_t)(s * PPS) * D4_;

    #pragma unroll
    for (int g = 0; g < PPS; g += 8) {
        float4 v[8];
        #pragma unroll
        for (int k = 0; k < 8; ++k)
            v[k] = rps[(size_t)(g + k) * D4_];
        #pragma unroll
        for (int k = 0; k < 8; k += 2) {
            #pragma unroll
            for (int j = 0; j < W_; ++j) {
                const bool b0 = (m[j] >> (g + k))     & 1u;  // uniform
                const bool b1 = (m[j] >> (g + k + 1)) & 1u;  // uniform
                // One VCC per bit gates FOUR cndmasks (amortized SALU).
                float sx0 = b0 ? v[k].x     : ninf;
                float sy0 = b0 ? v[k].y     : ninf;
                float sz0 = b0 ? v[k].z     : ninf;
                float sw0 = b0 ? v[k].w     : ninf;
                float sx1 = b1 ? v[k + 1].x : ninf;
                float sy1 = b1 ? v[k + 1].y : ninf;
                float sz1 = b1 ? v[k + 1].z : ninf;
                float sw1 = b1 ? v[k + 1].w : ninf;
                max3_inplace(acc[j].x, sx0, sx1);
                max3_inplace(acc[j].y, sy0, sy1);
                max3_inplace(acc[j].z, sz0, sz1);
                max3_inplace(acc[j].w, sw0, sw1);
            }
        }
    }

    // Merge the 8 segments via LDS (8 x 5 x 64 x 16B = 40 KB).
    __shared__ float4 sacc[SEGS][W_][64];
    #pragma unroll
    for (int j = 0; j < W_; ++j) sacc[s][j][lane] = acc[j];
    __syncthreads();

    // Wave j (< W_) finalizes word j. Serial fmaxf fold: compiler overlaps
    // ds_read latency under the chain with staggered lgkmcnt waits (the
    // R23 asm tree-fold pinned the schedule and regressed).
    if (s < W_) {
        const int j = s;
        float4 r = sacc[0][j][lane];
        #pragma unroll
        for (int seg = 1; seg < SEGS; ++seg) {
            r.x = fmaxf(r.x, sacc[seg][j][lane].x);
            r.y = fmaxf(r.y, sacc[seg][j][lane].y);
            r.z = fmaxf(r.z, sacc[seg][j][lane].z);
            r.w = fmaxf(r.w, sacc[seg][j][lane].w);
        }

        if (word_empty) {
            // Never taken for the fixed inputs; correct fallback = global
            // min over ALL of emb (reference min_value semantics).
            const float4* x = (const float4*)emb;
            const int n4 = (B_ * LP_ * D_) / 4;
            float mn = __uint_as_float(0x7F800000u);  // +inf
            for (int i = lane; i < n4; i += 64) {
                float4 vv = x[i];
                mn = fminf(mn, fminf(fminf(vv.x, vv.y), fminf(vv.z, vv.w)));
            }
            #pragma unroll
            for (int off = 32; off > 0; off >>= 1)
                mn = fminf(mn, __shfl_down(mn, off, 64));
            mn = __shfl(mn, 0, 64);
            r = make_float4(mn, mn, mn, mn);
        }

        // Write-once output: nontemporal dwordx4 (clang native vector type;
        // __builtin_nontemporal_store rejects HIP_vector_type).
        v4f* op = (v4f*)((float4*)out + (size_t)(b * LW_ + w0 + j) * D4_
                         + chunk * 64 + lane);
        v4f rv;
        rv.x = r.x; rv.y = r.y; rv.z = r.z; rv.w = r.w;
        __builtin_nontemporal_store(rv, op);
    }
}

extern "C" void kernel_launch(void* const* d_in, const int* in_sizes, int n_in,
                              void* d_out, int out_size, void* d_ws, size_t ws_size,
                              hipStream_t stream) {
    const float* emb = (const float*)d_in[0];
    const int*   p2w = (const int*)d_in[1];
    float*       out = (float*)d_out;
    (void)d_ws; (void)ws_size;

    word_max_scan<<<NBLK, 512, 0, stream>>>(emb, p2w, out);
}